// Round 6
// baseline (817.958 us; speedup 1.0000x reference)
//
#include <hip/hip_runtime.h>
#include <hip/hip_cooperative_groups.h>
#include <cstdint>
#include <cstddef>

namespace cg = cooperative_groups;

#define B_ 2
#define N_ 2048
#define D_ 64
#define E_ 2
#define T_ 5

typedef short bf16x8 __attribute__((ext_vector_type(8)));
typedef unsigned short u16x8 __attribute__((ext_vector_type(8)));
typedef float f32x16 __attribute__((ext_vector_type(16)));

__device__ __forceinline__ unsigned short f2bf(float f) {
    unsigned int x = __float_as_uint(f);
    x += 0x7FFFu + ((x >> 16) & 1u);
    return (unsigned short)(x >> 16);
}

// ---------------------------------------------------------------------------
// convert: adj fp32 (B,N,2*N*E) -> bf16 in MFMA-fragment-tile order.
// Abf[bd][rt][kt][lane][8]: lane&31 = row-in-tile, lane>>5 = k-half, 8 contig k.
// grid (64 rt, 8 k-chunks, 4 bd), 256 threads.
// ---------------------------------------------------------------------------
__global__ void convert_kernel(const float* __restrict__ adj, u16x8* __restrict__ Abf) {
    int rt = blockIdx.x, c = blockIdx.y, bd = blockIdx.z;
    int b = bd >> 1, dir = bd & 1;
    int tid = threadIdx.x;

    __shared__ __align__(16) unsigned short sb[32][520];   // row stride 1040 B

    const float* base = adj + ((size_t)(b * N_ + rt * 32)) * (2 * N_ * E_) + dir * (N_ * E_) + c * 512;

    #pragma unroll
    for (int p = 0; p < 4; ++p) {
        int r = p * 8 + (tid >> 5);
        int i = tid & 31;
        const float* rowp = base + (size_t)r * (2 * N_ * E_);
        #pragma unroll
        for (int j = 0; j < 4; ++j) {
            float4 f = *(const float4*)(rowp + i * 4 + j * 128);
            int kl = i * 4 + j * 128;
            sb[r][kl + 0] = f2bf(f.x);
            sb[r][kl + 1] = f2bf(f.y);
            sb[r][kl + 2] = f2bf(f.z);
            sb[r][kl + 3] = f2bf(f.w);
        }
    }
    __syncthreads();

    int l = tid & 63;
    int row = l & 31, khalf = l >> 5;
    int ktl0 = tid >> 6;
    u16x8* dst = Abf + ((size_t)(bd * 64 + rt) * 256 + c * 32 + ktl0) * 64 + l;
    #pragma unroll
    for (int q = 0; q < 8; ++q) {
        int ktl = ktl0 + q * 4;
        u16x8 v = *(const u16x8*)&sb[row][ktl * 16 + khalf * 8];
        dst[(size_t)q * 4 * 64] = v;
    }
}

// ---------------------------------------------------------------------------
// Fused cooperative kernel: 256 wgs x 512 thr (1 wg/CU). wg owns 16 nodes;
// h for those nodes lives in LDS across all T iterations.
// ---------------------------------------------------------------------------
struct SM {
    float hs[16][64];       // h for the wg's 16 nodes (persistent)
    float os[4][16][66];    // transform outputs per (dir,e)
    float sa[16][3][64];    // gru staging
    float red[4][2];        // output reduction
};

// transform + VT fragment emit for the wg's 16 nodes (reads sm->hs).
// Caller must have synced so hs is valid. Leaves os clobbered.
__device__ __forceinline__ void transform_emit(
        SM* sm, u16x8* VT,
        const float* W_in, const float* b_in,
        const float* W_out, const float* b_out,
        int b, int ktgl, int tid)
{
    int u = tid >> 6, lane = tid & 63;
    int dir = u & 1, e = (u >> 1) & 1, nh = u >> 2;
    const float* W    = (dir ? W_out : W_in) + e * D_ * D_;
    const float* bias = (dir ? b_out : b_in) + e * D_;
    int d = lane;
    float acc[8];
    #pragma unroll
    for (int i = 0; i < 8; ++i) acc[i] = bias[d];
    for (int k = 0; k < 64; ++k) {
        float wv = W[k * 64 + d];
        #pragma unroll
        for (int i = 0; i < 8; ++i) acc[i] = fmaf(sm->hs[nh * 8 + i][k], wv, acc[i]);
    }
    int de = dir * 2 + e;
    #pragma unroll
    for (int i = 0; i < 8; ++i) sm->os[de][nh * 8 + i][d] = acc[i];
    __syncthreads();

    // emit one fragment per 64-lane unit: (dir,e,sub)
    int sub = u >> 2;
    int dd = sub * 32 + (lane & 31);
    int nb = (lane >> 5) * 8;
    u16x8 o;
    #pragma unroll
    for (int j = 0; j < 8; ++j) o[j] = f2bf(sm->os[de][nb + j][dd]);
    int bd = b * 2 + dir;
    int ktg = e * 128 + ktgl;
    VT[((size_t)bd * 512 + ktg * 2 + sub) * 64 + lane] = o;
}

__device__ __forceinline__ void aggregate_phase(
        const bf16x8* Abf, const bf16x8* VT, float* apart, int wg, int tid)
{
    int rb = wg & 7, bd = (wg >> 3) & 3, sp = wg >> 5;
    int w = tid >> 6, lane = tid & 63;
    int rt = rb * 8 + w;
    int kt0 = sp * 32;
    const bf16x8* Ap = Abf + ((size_t)(bd * 64 + rt) * 256 + kt0) * 64 + lane;
    const bf16x8* Vp = VT + (size_t)bd * 32768 + (size_t)kt0 * 128 + lane;

    f32x16 acc0 = {}, acc1 = {};
    #pragma unroll 4
    for (int kk = 0; kk < 32; ++kk) {
        bf16x8 a  = Ap[(size_t)kk * 64];
        bf16x8 b0 = Vp[(size_t)kk * 128];
        bf16x8 b1 = Vp[(size_t)kk * 128 + 64];
        acc0 = __builtin_amdgcn_mfma_f32_32x32x16_bf16(a, b0, acc0, 0, 0, 0);
        acc1 = __builtin_amdgcn_mfma_f32_32x32x16_bf16(a, b1, acc1, 0, 0, 0);
    }
    float* Cp = apart + ((size_t)(sp * 4 + bd) * 2048) * 64;
    int col = lane & 31;
    int rbase = rt * 32 + 4 * (lane >> 5);
    #pragma unroll
    for (int reg = 0; reg < 16; ++reg) {
        int row = rbase + (reg & 3) + 8 * (reg >> 2);
        Cp[(size_t)row * 64 + col]      = acc0[reg];
        Cp[(size_t)row * 64 + col + 32] = acc1[reg];
    }
}

// gru for the wg's 16 nodes; each 64-lane wave handles 2 nodes (wave-local LDS).
__device__ __forceinline__ void gru_phase(
        SM* sm, const float* apart,
        const float* Wr, const float* br, const float* Wz, const float* bz,
        const float* Wh, const float* bh, int b, int n0, int tid)
{
    int u = tid >> 6, d = tid & 63;
    #pragma unroll
    for (int s = 0; s < 2; ++s) {
        int nl = u * 2 + s;
        int n = n0 + nl;
        float ain = 0.f, aout = 0.f;
        #pragma unroll
        for (int sp = 0; sp < 8; ++sp) {
            ain  += apart[(((size_t)(sp * 4 + b * 2    )) * 2048 + n) * 64 + d];
            aout += apart[(((size_t)(sp * 4 + b * 2 + 1)) * 2048 + n) * 64 + d];
        }
        float h_d = sm->hs[nl][d];
        sm->sa[nl][0][d] = ain;
        sm->sa[nl][1][d] = aout;
        sm->sa[nl][2][d] = h_d;
        // same-wave LDS writes are visible to the wave's subsequent reads
        float accr = br[d], accz = bz[d];
        #pragma unroll 8
        for (int k = 0; k < 64; ++k) {
            float a0 = sm->sa[nl][0][k], a1 = sm->sa[nl][1][k], a2 = sm->sa[nl][2][k];
            accr = fmaf(a0, Wr[k * 64 + d], accr);
            accr = fmaf(a1, Wr[(64 + k) * 64 + d], accr);
            accr = fmaf(a2, Wr[(128 + k) * 64 + d], accr);
            accz = fmaf(a0, Wz[k * 64 + d], accz);
            accz = fmaf(a1, Wz[(64 + k) * 64 + d], accz);
            accz = fmaf(a2, Wz[(128 + k) * 64 + d], accz);
        }
        float r = 1.0f / (1.0f + expf(-accr));
        float z = 1.0f / (1.0f + expf(-accz));
        sm->sa[nl][2][d] = r * h_d;
        float acch = bh[d];
        #pragma unroll 8
        for (int k = 0; k < 64; ++k) {
            float a0 = sm->sa[nl][0][k], a1 = sm->sa[nl][1][k], a2 = sm->sa[nl][2][k];
            acch = fmaf(a0, Wh[k * 64 + d], acch);
            acch = fmaf(a1, Wh[(64 + k) * 64 + d], acch);
            acch = fmaf(a2, Wh[(128 + k) * 64 + d], acch);
        }
        float hh = tanhf(acch);
        sm->hs[nl][d] = (1.0f - z) * h_d + z * hh;
    }
}

__device__ __forceinline__ void output_phase(
        SM* sm, const float* ann,
        const float* Wo1, const float* bo1, const float* Wo2, const float* bo2,
        float* out, int g0, int tid)
{
    int sub = tid >> 7, j = tid & 127;
    int wv = (tid >> 6) & 1;
    #pragma unroll
    for (int s = 0; s < 4; ++s) {
        int nl = sub * 4 + s;
        int g = g0 + nl;
        float acc = bo1[j];
        #pragma unroll
        for (int i = 0; i < 64; ++i) acc = fmaf(sm->hs[nl][i], Wo1[i * 128 + j], acc);
        #pragma unroll
        for (int i = 0; i < 16; ++i) acc = fmaf(ann[(size_t)g * 16 + i], Wo1[(64 + i) * 128 + j], acc);
        float y = 1.0f / (1.0f + expf(-acc));
        float v = y * Wo2[j];
        #pragma unroll
        for (int off = 32; off > 0; off >>= 1) v += __shfl_down(v, off, 64);
        if ((tid & 63) == 0) sm->red[sub][wv] = v;
        __syncthreads();
        if (j == 0) out[g] = sm->red[sub][0] + sm->red[sub][1] + bo2[0];
        __syncthreads();
    }
}

__global__ void __launch_bounds__(512, 1) ggnn_coop(
        const float* prop, const float* ann,
        const bf16x8* Abf, u16x8* VT, float* apart,
        const float* W_in, const float* b_in,
        const float* W_out, const float* b_out,
        const float* Wr, const float* br,
        const float* Wz, const float* bz,
        const float* Wh, const float* bh,
        const float* Wo1, const float* bo1,
        const float* Wo2, const float* bo2,
        float* out)
{
    cg::grid_group grid = cg::this_grid();
    __shared__ SM sm;
    int wg = blockIdx.x, tid = threadIdx.x;
    int g0 = wg * 16;
    int b = g0 >> 11;
    int n0 = g0 & 2047;
    int ktgl = n0 >> 4;

    // load h0 = prop for the wg's 16 nodes
    #pragma unroll
    for (int i = 0; i < 2; ++i) {
        int idx = tid + i * 512;
        sm.hs[idx >> 6][idx & 63] = prop[(size_t)g0 * 64 + idx];
    }
    __syncthreads();
    transform_emit(&sm, VT, W_in, b_in, W_out, b_out, b, ktgl, tid);
    grid.sync();

    for (int t = 0; t < T_; ++t) {
        aggregate_phase(Abf, (const bf16x8*)VT, apart, wg, tid);
        grid.sync();
        gru_phase(&sm, apart, Wr, br, Wz, bz, Wh, bh, b, n0, tid);
        __syncthreads();
        if (t < T_ - 1) {
            transform_emit(&sm, VT, W_in, b_in, W_out, b_out, b, ktgl, tid);
            grid.sync();
        }
    }
    __syncthreads();
    output_phase(&sm, ann, Wo1, bo1, Wo2, bo2, out, g0, tid);
}

// ---------------------------------------------------------------------------
extern "C" void kernel_launch(void* const* d_in, const int* in_sizes, int n_in,
                              void* d_out, int out_size, void* d_ws, size_t ws_size,
                              hipStream_t stream) {
    const float* prop = (const float*)d_in[0];
    const float* ann  = (const float*)d_in[1];
    const float* adj  = (const float*)d_in[2];
    const float* W_in = (const float*)d_in[3];
    const float* b_in = (const float*)d_in[4];
    const float* W_out= (const float*)d_in[5];
    const float* b_out= (const float*)d_in[6];
    const float* Wr   = (const float*)d_in[7];
    const float* br   = (const float*)d_in[8];
    const float* Wz   = (const float*)d_in[9];
    const float* bz   = (const float*)d_in[10];
    const float* Wh   = (const float*)d_in[11];
    const float* bh   = (const float*)d_in[12];
    const float* Wo1  = (const float*)d_in[13];
    const float* bo1  = (const float*)d_in[14];
    const float* Wo2  = (const float*)d_in[15];
    const float* bo2  = (const float*)d_in[16];
    float* out = (float*)d_out;

    char* ws = (char*)d_ws;
    u16x8* Abf    = (u16x8*)ws;                     // 64 MiB
    u16x8* VT     = (u16x8*)(ws + (64ull << 20));   // 2 MiB
    float* apart  = (float*)(ws + (66ull << 20));   // 16 MiB

    convert_kernel<<<dim3(64, 8, 4), 256, 0, stream>>>(adj, Abf);

    const bf16x8* Abf_c = (const bf16x8*)Abf;
    void* args[] = {
        (void*)&prop, (void*)&ann, (void*)&Abf_c, (void*)&VT, (void*)&apart,
        (void*)&W_in, (void*)&b_in, (void*)&W_out, (void*)&b_out,
        (void*)&Wr, (void*)&br, (void*)&Wz, (void*)&bz, (void*)&Wh, (void*)&bh,
        (void*)&Wo1, (void*)&bo1, (void*)&Wo2, (void*)&bo2, (void*)&out
    };
    hipLaunchCooperativeKernel((void*)ggnn_coop, dim3(256), dim3(512),
                               args, 0, stream);
}

// Round 7
// 490.664 us; speedup vs baseline: 1.6670x; 1.6670x over previous
//
#include <hip/hip_runtime.h>
#include <cstdint>
#include <cstddef>

#define B_ 2
#define N_ 2048
#define D_ 64
#define E_ 2
#define T_ 5

typedef short bf16x8 __attribute__((ext_vector_type(8)));
typedef unsigned short u16x8 __attribute__((ext_vector_type(8)));
typedef float f32x16 __attribute__((ext_vector_type(16)));

__device__ __forceinline__ unsigned short f2bf(float f) {
    unsigned int x = __float_as_uint(f);
    x += 0x7FFFu + ((x >> 16) & 1u);
    return (unsigned short)(x >> 16);
}

// ---------------------------------------------------------------------------
// convert: adj fp32 (B,N,2*N*E) -> bf16 in MFMA-fragment-tile order.
// Abf[bd][rt][kt][lane][8]: lane&31 = row-in-tile, lane>>5 = k-half, 8 contig k.
// grid (64 rt, 8 k-chunks, 4 bd), 256 threads.
// ---------------------------------------------------------------------------
__global__ void convert_kernel(const float* __restrict__ adj, u16x8* __restrict__ Abf) {
    int rt = blockIdx.x, c = blockIdx.y, bd = blockIdx.z;
    int b = bd >> 1, dir = bd & 1;
    int tid = threadIdx.x;

    __shared__ __align__(16) unsigned short sb[32][520];   // row stride 1040 B

    const float* base = adj + ((size_t)(b * N_ + rt * 32)) * (2 * N_ * E_) + dir * (N_ * E_) + c * 512;

    #pragma unroll
    for (int p = 0; p < 4; ++p) {
        int r = p * 8 + (tid >> 5);
        int i = tid & 31;
        const float* rowp = base + (size_t)r * (2 * N_ * E_);
        #pragma unroll
        for (int j = 0; j < 4; ++j) {
            float4 f = *(const float4*)(rowp + i * 4 + j * 128);
            int kl = i * 4 + j * 128;
            sb[r][kl + 0] = f2bf(f.x);
            sb[r][kl + 1] = f2bf(f.y);
            sb[r][kl + 2] = f2bf(f.z);
            sb[r][kl + 3] = f2bf(f.w);
        }
    }
    __syncthreads();

    int l = tid & 63;
    int row = l & 31, khalf = l >> 5;
    int ktl0 = tid >> 6;
    u16x8* dst = Abf + ((size_t)(bd * 64 + rt) * 256 + c * 32 + ktl0) * 64 + l;
    #pragma unroll
    for (int q = 0; q < 8; ++q) {
        int ktl = ktl0 + q * 4;
        u16x8 v = *(const u16x8*)&sb[row][ktl * 16 + khalf * 8];
        dst[(size_t)q * 4 * 64] = v;
    }
}

// ---------------------------------------------------------------------------
// transform0: VT from prop (t=0 only). grid (32 n-tiles, 8), 256 thr.
// VT[bd][ktg][sub][lane][8]: node k = ktg*16+(lane>>5)*8+j, col d = sub*32+(lane&31)
// ---------------------------------------------------------------------------
__global__ void transform0_kernel(const float* __restrict__ h,
                                  const float* __restrict__ W_in, const float* __restrict__ b_in,
                                  const float* __restrict__ W_out, const float* __restrict__ b_out,
                                  u16x8* __restrict__ VT) {
    int y = blockIdx.y;
    int e = y & 1, dir = (y >> 1) & 1, b = y >> 2;
    int bd = y >> 1;
    const float* W = (dir ? W_out : W_in) + e * D_ * D_;
    const float* bias = (dir ? b_out : b_in) + e * D_;
    int n0 = blockIdx.x * 64;

    __shared__ float hs[64][65];
    __shared__ float Ws[64][64];
    __shared__ float os[64][65];

    int tid = threadIdx.x;
    #pragma unroll
    for (int i = 0; i < 16; ++i) {
        int idx = tid + 256 * i;
        int r = idx >> 6, c = idx & 63;
        hs[r][c] = h[((size_t)(b * N_ + n0 + r)) * D_ + c];
        Ws[r][c] = W[idx];
    }
    __syncthreads();

    int g = tid >> 6, l = tid & 63;
    float acc[16];
    #pragma unroll
    for (int j = 0; j < 16; ++j) acc[j] = bias[g * 16 + j];
    for (int k = 0; k < 64; ++k) {
        float hv = hs[l][k];
        #pragma unroll
        for (int j = 0; j < 16; ++j) acc[j] = fmaf(hv, Ws[k][g * 16 + j], acc[j]);
    }
    #pragma unroll
    for (int j = 0; j < 16; ++j) os[l][g * 16 + j] = acc[j];
    __syncthreads();

    #pragma unroll
    for (int c = 0; c < 2; ++c) {
        int chunk = tid + 256 * c;
        int kt_local = chunk >> 7;
        int sub = (chunk >> 6) & 1;
        int ln = chunk & 63;
        int d = sub * 32 + (ln & 31);
        int nbase = kt_local * 16 + (ln >> 5) * 8;
        u16x8 o;
        #pragma unroll
        for (int j = 0; j < 8; ++j) o[j] = f2bf(os[nbase + j][d]);
        int ktg = e * 128 + blockIdx.x * 4 + kt_local;
        VT[((size_t)bd * 512 + ktg * 2 + sub) * 64 + ln] = o;
    }
}

// ---------------------------------------------------------------------------
// aggregate: apart[split][bd] (2048x64) = A_bf16 @ V_bf16 via MFMA.
// grid (8 rowblocks, 4 bd, 8 splits), 512 thr = 8 waves; wave = 32 rows.
// ---------------------------------------------------------------------------
__global__ void __launch_bounds__(512, 2) aggregate_kernel(
        const bf16x8* __restrict__ Abf, const bf16x8* __restrict__ VT,
        float* __restrict__ apart) {
    int bx = blockIdx.x;
    int bd = blockIdx.y;
    int sp = blockIdx.z;
    int tid = threadIdx.x;
    int w = tid >> 6, lane = tid & 63;
    int rt = bx * 8 + w;
    int kt0 = sp * 32;

    const bf16x8* Ap = Abf + ((size_t)(bd * 64 + rt) * 256 + kt0) * 64 + lane;
    const bf16x8* Vp = VT + (size_t)bd * 32768 + (size_t)kt0 * 128 + lane;

    f32x16 acc0 = {}, acc1 = {};
    #pragma unroll 4
    for (int kk = 0; kk < 32; ++kk) {
        bf16x8 a  = Ap[(size_t)kk * 64];
        bf16x8 b0 = Vp[(size_t)kk * 128];
        bf16x8 b1 = Vp[(size_t)kk * 128 + 64];
        acc0 = __builtin_amdgcn_mfma_f32_32x32x16_bf16(a, b0, acc0, 0, 0, 0);
        acc1 = __builtin_amdgcn_mfma_f32_32x32x16_bf16(a, b1, acc1, 0, 0, 0);
    }

    float* Cp = apart + ((size_t)(sp * 4 + bd) * 2048) * 64;
    int col = lane & 31;
    int rbase = rt * 32 + 4 * (lane >> 5);
    #pragma unroll
    for (int reg = 0; reg < 16; ++reg) {
        int row = rbase + (reg & 3) + 8 * (reg >> 2);
        Cp[(size_t)row * 64 + col]      = acc0[reg];
        Cp[(size_t)row * 64 + col + 32] = acc1[reg];
    }
}

// ---------------------------------------------------------------------------
// gru core: one 64-lane unit per node (16 nodes/wg, 1024 thr).
// Reads h_old from h_in, apart splits; writes h_new into hs[] (LDS).
// ---------------------------------------------------------------------------
__device__ __forceinline__ void gru_core(
        const float* __restrict__ h_in, const float* __restrict__ apart,
        const float* __restrict__ Wr, const float* __restrict__ br,
        const float* __restrict__ Wz, const float* __restrict__ bz,
        const float* __restrict__ Wh, const float* __restrict__ bh,
        float sa[16][3][64], float hs[16][64],
        int b, int n0, int g0, int tid)
{
    int nl = tid >> 6, d = tid & 63;
    int n = n0 + nl;
    float ain = 0.f, aout = 0.f;
    #pragma unroll
    for (int sp = 0; sp < 8; ++sp) {
        ain  += apart[(((size_t)(sp * 4 + b * 2    )) * 2048 + n) * 64 + d];
        aout += apart[(((size_t)(sp * 4 + b * 2 + 1)) * 2048 + n) * 64 + d];
    }
    float h_d = h_in[((size_t)g0 + nl) * 64 + d];
    sa[nl][0][d] = ain;
    sa[nl][1][d] = aout;
    sa[nl][2][d] = h_d;
    // same-wave LDS write->read ordering is handled by HW waitcnts
    float accr = br[d], accz = bz[d];
    #pragma unroll 8
    for (int k = 0; k < 64; ++k) {
        float a0 = sa[nl][0][k], a1 = sa[nl][1][k], a2 = sa[nl][2][k];
        accr = fmaf(a0, Wr[k * 64 + d], accr);
        accr = fmaf(a1, Wr[(64 + k) * 64 + d], accr);
        accr = fmaf(a2, Wr[(128 + k) * 64 + d], accr);
        accz = fmaf(a0, Wz[k * 64 + d], accz);
        accz = fmaf(a1, Wz[(64 + k) * 64 + d], accz);
        accz = fmaf(a2, Wz[(128 + k) * 64 + d], accz);
    }
    float r = 1.0f / (1.0f + expf(-accr));
    float z = 1.0f / (1.0f + expf(-accz));
    sa[nl][2][d] = r * h_d;
    float acch = bh[d];
    #pragma unroll 8
    for (int k = 0; k < 64; ++k) {
        float a0 = sa[nl][0][k], a1 = sa[nl][1][k], a2 = sa[nl][2][k];
        acch = fmaf(a0, Wh[k * 64 + d], acch);
        acch = fmaf(a1, Wh[(64 + k) * 64 + d], acch);
        acch = fmaf(a2, Wh[(128 + k) * 64 + d], acch);
    }
    float hh = tanhf(acch);
    hs[nl][d] = (1.0f - z) * h_d + z * hh;
}

// ---------------------------------------------------------------------------
// gru_mid: gru + h write + VT fragment emit for the wg's 16 nodes.
// grid 256 wgs x 1024 thr; wg owns nodes g0=wg*16 .. +15.
// ---------------------------------------------------------------------------
__global__ void __launch_bounds__(1024, 1) gru_mid_kernel(
        const float* __restrict__ h_in, float* __restrict__ h_out,
        const float* __restrict__ apart,
        const float* __restrict__ Wr, const float* __restrict__ br,
        const float* __restrict__ Wz, const float* __restrict__ bz,
        const float* __restrict__ Wh, const float* __restrict__ bh,
        const float* __restrict__ W_in, const float* __restrict__ b_in,
        const float* __restrict__ W_out, const float* __restrict__ b_out,
        u16x8* __restrict__ VT)
{
    __shared__ float sa[16][3][64];
    __shared__ float hs[16][64];
    __shared__ float os[4][16][66];

    int wg = blockIdx.x, tid = threadIdx.x;
    int g0 = wg * 16;
    int b = g0 >> 11, n0 = g0 & 2047;
    int ktgl = n0 >> 4;

    gru_core(h_in, apart, Wr, br, Wz, bz, Wh, bh, sa, hs, b, n0, g0, tid);

    // write h_new to global (next iteration's h_in)
    {
        int nl = tid >> 6, d = tid & 63;
        h_out[((size_t)g0 + nl) * 64 + d] = hs[nl][d];
    }
    __syncthreads();

    // transform tail: unit u (0..15): de = u&3 (dir*2+e), nodes q*4..q*4+3 (q=u>>2)
    int u = tid >> 6, lane = tid & 63;
    {
        int de = u & 3, q = u >> 2;
        int dir = de >> 1, e = de & 1;
        const float* W    = (dir ? W_out : W_in) + e * D_ * D_;
        const float* bias = (dir ? b_out : b_in) + e * D_;
        int d = lane;
        float acc[4];
        #pragma unroll
        for (int i = 0; i < 4; ++i) acc[i] = bias[d];
        for (int k = 0; k < 64; ++k) {
            float wv = W[k * 64 + d];
            #pragma unroll
            for (int i = 0; i < 4; ++i) acc[i] = fmaf(hs[q * 4 + i][k], wv, acc[i]);
        }
        #pragma unroll
        for (int i = 0; i < 4; ++i) os[de][q * 4 + i][d] = acc[i];
    }
    __syncthreads();

    // emit: units 0..7: de = u>>1, sub = u&1
    if (u < 8) {
        int de = u >> 1, sub = u & 1;
        int dir = de >> 1, e = de & 1;
        int dd = sub * 32 + (lane & 31);
        int nb = (lane >> 5) * 8;
        u16x8 o;
        #pragma unroll
        for (int j = 0; j < 8; ++j) o[j] = f2bf(os[de][nb + j][dd]);
        int bd = b * 2 + dir;
        int ktg = e * 128 + ktgl;
        VT[((size_t)bd * 512 + ktg * 2 + sub) * 64 + lane] = o;
    }
}

// ---------------------------------------------------------------------------
// gru_last: gru + output head (no VT emit, no h write).
// grid 256 wgs x 1024 thr.
// ---------------------------------------------------------------------------
__global__ void __launch_bounds__(1024, 1) gru_last_kernel(
        const float* __restrict__ h_in,
        const float* __restrict__ apart,
        const float* __restrict__ Wr, const float* __restrict__ br,
        const float* __restrict__ Wz, const float* __restrict__ bz,
        const float* __restrict__ Wh, const float* __restrict__ bh,
        const float* __restrict__ ann,
        const float* __restrict__ Wo1, const float* __restrict__ bo1,
        const float* __restrict__ Wo2, const float* __restrict__ bo2,
        float* __restrict__ out)
{
    __shared__ float sa[16][3][64];
    __shared__ float hs[16][64];
    __shared__ float red[8][2][2];

    int wg = blockIdx.x, tid = threadIdx.x;
    int g0 = wg * 16;
    int b = g0 >> 11, n0 = g0 & 2047;

    gru_core(h_in, apart, Wr, br, Wz, bz, Wh, bh, sa, hs, b, n0, g0, tid);
    __syncthreads();

    // output head: sub = tid>>7 (8 groups of 128 j); each sub handles 2 nodes
    int sub = tid >> 7, j = tid & 127;
    int wv = (tid >> 6) & 1;
    #pragma unroll
    for (int s = 0; s < 2; ++s) {
        int nl = sub * 2 + s;
        int g = g0 + nl;
        float acc = bo1[j];
        #pragma unroll
        for (int i = 0; i < 64; ++i) acc = fmaf(hs[nl][i], Wo1[i * 128 + j], acc);
        #pragma unroll
        for (int i = 0; i < 16; ++i) acc = fmaf(ann[(size_t)g * 16 + i], Wo1[(64 + i) * 128 + j], acc);
        float y = 1.0f / (1.0f + expf(-acc));
        float v = y * Wo2[j];
        #pragma unroll
        for (int off = 32; off > 0; off >>= 1) v += __shfl_down(v, off, 64);
        if ((tid & 63) == 0) red[sub][wv][s] = v;
    }
    __syncthreads();
    if (j == 0) {
        #pragma unroll
        for (int s = 0; s < 2; ++s)
            out[g0 + sub * 2 + s] = red[sub][0][s] + red[sub][1][s] + bo2[0];
    }
}

// ---------------------------------------------------------------------------
extern "C" void kernel_launch(void* const* d_in, const int* in_sizes, int n_in,
                              void* d_out, int out_size, void* d_ws, size_t ws_size,
                              hipStream_t stream) {
    const float* prop = (const float*)d_in[0];
    const float* ann  = (const float*)d_in[1];
    const float* adj  = (const float*)d_in[2];
    const float* W_in = (const float*)d_in[3];
    const float* b_in = (const float*)d_in[4];
    const float* W_out= (const float*)d_in[5];
    const float* b_out= (const float*)d_in[6];
    const float* Wr   = (const float*)d_in[7];
    const float* br   = (const float*)d_in[8];
    const float* Wz   = (const float*)d_in[9];
    const float* bz   = (const float*)d_in[10];
    const float* Wh   = (const float*)d_in[11];
    const float* bh   = (const float*)d_in[12];
    const float* Wo1  = (const float*)d_in[13];
    const float* bo1  = (const float*)d_in[14];
    const float* Wo2  = (const float*)d_in[15];
    const float* bo2  = (const float*)d_in[16];
    float* out = (float*)d_out;

    char* ws = (char*)d_ws;
    u16x8* Abf    = (u16x8*)ws;                     // 64 MiB
    u16x8* VT     = (u16x8*)(ws + (64ull << 20));   // 2 MiB
    float* apart  = (float*)(ws + (66ull << 20));   // 16 MiB
    float* h      = (float*)(ws + (82ull << 20));   // 1 MiB

    convert_kernel<<<dim3(64, 8, 4), 256, 0, stream>>>(adj, Abf);
    transform0_kernel<<<dim3(32, 8), 256, 0, stream>>>(
        prop, W_in, b_in, W_out, b_out, VT);

    for (int t = 0; t < T_; ++t) {
        aggregate_kernel<<<dim3(8, 4, 8), 512, 0, stream>>>(
            (const bf16x8*)Abf, (const bf16x8*)VT, apart);
        const float* h_in = (t == 0) ? prop : h;
        if (t < T_ - 1) {
            gru_mid_kernel<<<dim3(256), 1024, 0, stream>>>(
                h_in, h, apart, Wr, br, Wz, bz, Wh, bh,
                W_in, b_in, W_out, b_out, VT);
        } else {
            gru_last_kernel<<<dim3(256), 1024, 0, stream>>>(
                h_in, apart, Wr, br, Wz, bz, Wh, bh,
                ann, Wo1, bo1, Wo2, bo2, out);
        }
    }
}